// Round 9
// baseline (155.751 us; speedup 1.0000x reference)
//
#include <hip/hip_runtime.h>
#include <math.h>

#ifndef M_PI
#define M_PI 3.14159265358979323846
#endif

#define NS 7      // NUM_SPHERICAL
#define NK 6      // NUM_RADIAL
#define GT 64     // triplets per tile
#define BT 256    // threads per block
#define TPB 4     // tiles per block (pipelined)
#define NC (NS*NS)   // 49
#define NR (NS*NK)   // 42
#define NF2 147      // float2 per triplet row (294/2)

typedef float f32x2 __attribute__((ext_vector_type(2)));
typedef float f32x4 __attribute__((ext_vector_type(4)));

// raw workgroup barrier: orders LDS (lgkmcnt) but leaves global stores in
// flight (no vmcnt(0) drain — that drain was round 8's 28us regression).
__device__ __forceinline__ void barrier_lds_only() {
  asm volatile("s_waitcnt lgkmcnt(0)" ::: "memory");
  __builtin_amdgcn_s_barrier();
  __builtin_amdgcn_sched_barrier(0);
}

// tab layout (floats): [0..41] zeros (l*6+j), [42..83] norm, [84..132] coef(49)

// ---------------- setup (f32 hardware trig, ~1us) ---------------------------
__device__ void jl_pair_f(float x, int l, float& jl, float& jm1) {
  float s, c;
  __sincosf(x, &s, &c);
  float invx = 1.0f / x;
  float j0 = s * invx, jm = c * invx;
  if (l == 0) { jl = j0; jm1 = jm; return; }
  float j1 = (s * invx - c) * invx;
  for (int ll = 2; ll <= l; ++ll) {
    float t = (2.0f * ll - 1.0f) * invx * j1 - j0;
    j0 = j1; j1 = t;
  }
  jl = j1; jm1 = j0;
}

__global__ void setup_kernel(float* tab) {
  int id = threadIdx.x;
  if (id < NS * NK) {
    int l = id / NK, j = id % NK;
    float nu = l + 0.5f, mu = 4.0f * nu * nu;
    float b  = ((float)(j + 1) + 0.5f * nu - 0.25f) * (float)M_PI;
    float b8 = 8.0f * b;
    float x = b - (mu - 1.0f) / b8
                - 4.0f * (mu - 1.0f) * (7.0f * mu - 31.0f) / (3.0f * b8 * b8 * b8)
                - 32.0f * (mu - 1.0f) * (83.0f * mu * mu - 982.0f * mu + 3779.0f) /
                  (15.0f * b8 * b8 * b8 * b8 * b8);
    float jl, jm1;
    for (int it = 0; it < 5; ++it) {
      jl_pair_f(x, l, jl, jm1);
      float dj = jm1 - (l + 1.0f) / x * jl;   // j_l'(x)
      x -= jl / dj;
    }
    tab[id] = x;
    jl_pair_f(x, l, jl, jm1);
    float jp1 = (2.0f * l + 1.0f) / x * jl - jm1;   // j_{l+1}(x)
    tab[NS * NK + id] = sqrtf(2.0f) / fabsf(jp1);
  }
  if (id < NC) {
    double v;
    if (id == 0) {
      v = 0.5 / sqrt(M_PI);
    } else {
      int l = 1;
      while ((l + 1) * (l + 1) <= id) ++l;
      int m  = id - l * l - l;
      int am = m < 0 ? -m : m;
      double fr = 1.0;
      for (int i2 = l - am + 1; i2 <= l + am; ++i2) fr *= (double)i2;
      double pref = sqrt((2.0 * l + 1.0) / (4.0 * M_PI * fr));
      v = (m != 0) ? sqrt(2.0) * pref : pref;
    }
    tab[2 * NS * NK + id] = (float)v;
  }
}

// ---------------- main kernel: 4-tile double-buffered pipeline --------------
__global__ __launch_bounds__(BT, 3) void torsion_kernel(
    const float* __restrict__ dist, const float* __restrict__ angle,
    const float* __restrict__ phi, const int* __restrict__ idx_kj,
    const float* __restrict__ tab, float* __restrict__ out, int T) {
  __shared__ float s_cbf[2][GT][NC];                    // 2 x 64 x 49
  __shared__ __align__(8) float s_rbf[2][GT][NR];       // 2 x 64 x 42
  __shared__ float s_d[2][GT];
  __shared__ float s_tab[133];
  __shared__ unsigned s_map2[NF2];  // packed map(cc) | map((cc+1)%147)<<16

  const int tid   = threadIdx.x;
  const int ntt   = (T + GT - 1) / GT;
  const int tile0 = blockIdx.x * TPB;
  if (tile0 >= ntt) return;

  if (tid < 133) s_tab[tid] = tab[tid];
  if (tid < NF2) {
    auto mk = [](int cc) {
      int ii = (cc * 3121) >> 16;        // cc/21, cc<147
      int rem2 = cc - 21 * ii;
      int jj = (rem2 * 86) >> 8;         // rem2/3, rem2<21
      return (unsigned)((ii * NS + jj) | (rem2 << 8));
    };
    int cc1 = tid + 1; if (cc1 == NF2) cc1 = 0;
    s_map2[tid] = mk(tid) | (mk(cc1) << 16);
  }

  // ---- prologue: prefetch tile0 inputs ----
  float a0 = 0.0f, p0 = 0.0f;
  if (tid < GT) {
    int t = tile0 * GT + tid;
    float dd = 1.0f;
    if (t < T) {
      a0 = angle[t]; p0 = phi[t];
      dd = dist[idx_kj[t]] * 0.2f;     // /CUTOFF
    }
    s_d[0][tid] = dd;
  }
  __syncthreads();    // prologue: no stores in flight yet, full sync is fine

  // ---- persistent store maps (tid-only dependent, reused for all tiles) ----
  unsigned m[18];
  int k_st = tid, p_st = 0;
  if (k_st >= NF2) { k_st -= NF2; p_st = 1; }
  {
    int cc = k_st << 1; if (cc >= NF2) cc -= NF2;
#pragma unroll
    for (int it = 0; it < 18; ++it) {
      m[it] = s_map2[cc];
      cc += 71; if (cc >= NF2) cc -= NF2;
    }
  }

  // ---- compute phase (lambda, buffer-indexed) ----
  auto COMPUTE = [&](int b, int ti, float a, float ph) {
    if (tid < GT) {
      if (ti * GT + tid < T) {
        float z = cosf(a), s = sinf(a);
        float sp, cp;
        sincosf(ph, &sp, &cp);
        float cmv[NS], smv[NS];
        cmv[0] = 1.0f; smv[0] = 0.0f;
        cmv[1] = cp;   smv[1] = sp;
#pragma unroll
        for (int mm = 2; mm < NS; ++mm) {
          cmv[mm] = 2.0f * cp * cmv[mm - 1] - cmv[mm - 2];
          smv[mm] = 2.0f * cp * smv[mm - 1] - smv[mm - 2];
        }
        const float* coef = s_tab + 2 * NR;
        float* crow = s_cbf[b][tid];
        float pmm = 1.0f;
#pragma unroll
        for (int mm = 0; mm < NS; ++mm) {
          float pl1 = pmm, pl2 = 0.0f;
#pragma unroll
          for (int l = mm; l < NS; ++l) {
            float plm;
            if (l == mm)          plm = pmm;
            else if (l == mm + 1) plm = (float)(2 * mm + 1) * z * pmm;
            else                  plm = ((float)(2 * l - 1) * z * pl1 -
                                         (float)(l + mm - 1) * pl2) *
                                        (float)(1.0 / (double)(l - mm));
            int cpn = l * l + l + mm;
            if (mm == 0) {
              crow[cpn] = coef[cpn] * plm;
            } else {
              crow[cpn] = coef[cpn] * cmv[mm] * plm;
              crow[l * l + l - mm] = coef[l * l + l - mm] * smv[mm] * plm;
            }
            pl2 = pl1; pl1 = plm;
          }
          pmm = (float)(-1 - 2 * mm) * s * pmm;   // P[m+1][m+1]
        }
      }
    } else {
      // rbf: threads 64..255 cover 64*42 = 2688 = 14*192 items
      int j  = tid - 64;
      int t  = j / NR;
      int cc = j - NR * t;
      int i2 = j;
      float* rlin = &s_rbf[b][0][0];
      const float* sd = s_d[b];
#pragma unroll 2
      for (int it = 0; it < 14; ++it) {
        int l = (cc * 43) >> 8;      // cc/6 for cc<42
        float x = sd[t] * s_tab[cc];
        float sx, cx;
        sincosf(x, &sx, &cx);
        float invx = 1.0f / x;
        float jm = sx * invx;
        float jc;
        if (l == 0) jc = jm;
        else {
          jc = (sx * invx - cx) * invx;
#pragma unroll
          for (int ll = 2; ll <= 6; ++ll) {
            if (ll <= l) {
              float tt = (float)(2 * ll - 1) * invx * jc - jm;
              jm = jc; jc = tt;
            }
          }
        }
        rlin[i2] = s_tab[NR + cc] * jc;
        i2 += 192;
        cc += 24; t += 4;            // 192 = 4*42 + 24
        if (cc >= NR) { cc -= NR; ++t; }
      }
    }
  };

  COMPUTE(0, tile0, a0, p0);

  // ---- tile loop: prefetch(k+1) | store(k) | compute(k+1) ----
  // barriers are LDS-only: tile k's global stores stay in flight under
  // tile k+1's compute (no vmcnt(0) drain in the loop).
  for (int k2 = 0; k2 < TPB; ++k2) {
    int ti = tile0 + k2;
    if (ti >= ntt) break;
    int cur = k2 & 1;
    bool havenext = (k2 + 1 < TPB) && (ti + 1 < ntt);

    // prefetch next tile inputs into registers (latency hides under store)
    float a1 = 0.0f, p1 = 0.0f, dd1 = 1.0f;
    if (havenext && tid < GT) {
      int t1 = (ti + 1) * GT + tid;
      if (t1 < T) {
        a1 = angle[t1]; p1 = phi[t1];
        dd1 = dist[idx_kj[t1]] * 0.2f;
      }
    }
    barrier_lds_only();                  // A: buf[cur] compute visible

    // ---- store tile ti from buf[cur] ----
    int nt = min(GT, T - ti * GT);
    const f32x2* r2 = (const f32x2*)&s_rbf[cur][0][0];
    const float (*cb)[NC] = s_cbf[cur];

    if (nt == GT) {
      f32x4* o4 = (f32x4*)out + (size_t)ti * 4704 + tid;   // 64*294/4

      float cva[3], cvb[3];
      f32x2 rva[3], rvb[3];
      int ki = k_st, pi = p_st;

      auto ISSUE = [&](int slot, int it) {
        int t2 = pi << 1;
        int ta = t2 + (ki >= 74 ? 1 : 0);
        int tb = t2 + (ki >= 73 ? 1 : 0);
        unsigned mp = m[it];
        unsigned i0 = mp & 0xffu,          r0 = (mp >> 8) & 0xffu;
        unsigned i1 = (mp >> 16) & 0xffu,  r1 = mp >> 24;
        cva[slot] = cb[ta][i0];
        rva[slot] = r2[ta * 21 + r0];
        cvb[slot] = cb[tb][i1];
        rvb[slot] = r2[tb * 21 + r1];
        ki += 109; ++pi;
        if (ki >= NF2) { ki -= NF2; ++pi; }
      };

      ISSUE(0, 0);
      ISSUE(1, 1);
#pragma unroll
      for (int it = 0; it < 18; ++it) {
        if (it + 2 < 18) ISSUE((it + 2) % 3, it + 2);
        int sl = it % 3;
        f32x4 ov = {cva[sl] * rva[sl].x, cva[sl] * rva[sl].y,
                    cvb[sl] * rvb[sl].x, cvb[sl] * rvb[sl].y};
        __builtin_nontemporal_store(ov, o4 + it * 256);
      }

      if (tid < 96) {                    // tail: 18*256 + 96 = 4704
        int cc = ki << 1; if (cc >= NF2) cc -= NF2;
        unsigned mp = s_map2[cc];
        int t2 = pi << 1;
        int ta = t2 + (ki >= 74 ? 1 : 0);
        int tb = t2 + (ki >= 73 ? 1 : 0);
        unsigned i0 = mp & 0xffu,          r0 = (mp >> 8) & 0xffu;
        unsigned i1 = (mp >> 16) & 0xffu,  r1 = mp >> 24;
        float cv0 = cb[ta][i0];
        f32x2 rv0 = r2[ta * 21 + r0];
        float cv1 = cb[tb][i1];
        f32x2 rv1 = r2[tb * 21 + r1];
        f32x4 ov = {cv0 * rv0.x, cv0 * rv0.y, cv1 * rv1.x, cv1 * rv1.y};
        __builtin_nontemporal_store(ov, o4 + 18 * 256);
      }
    } else {
      // partial tile: float2 path
      f32x2* o2 = (f32x2*)out + (size_t)ti * GT * NF2;
      int tot = nt * NF2;
      for (int i = tid; i < tot; i += BT) {
        int t  = i / NF2;
        int c2 = i - NF2 * t;
        unsigned mp = s_map2[c2] & 0xffffu;
        float cv = cb[t][mp & 0xffu];
        f32x2 rv = r2[t * 21 + (mp >> 8)];
        f32x2 ov = cv * rv;
        __builtin_nontemporal_store(ov, o2 + i);
      }
    }

    if (havenext && tid < GT) s_d[(k2 + 1) & 1][tid] = dd1;
    barrier_lds_only();                  // B: buf[cur] LDS reads retired
    if (havenext) COMPUTE((k2 + 1) & 1, ti + 1, a1, p1);
  }
}

// ---------------- launch ----------------------------------------------------
extern "C" void kernel_launch(void* const* d_in, const int* in_sizes, int n_in,
                              void* d_out, int out_size, void* d_ws, size_t ws_size,
                              hipStream_t stream) {
  const float* dist  = (const float*)d_in[0];
  const float* angle = (const float*)d_in[1];
  const float* phi   = (const float*)d_in[2];
  const int*   idx   = (const int*)d_in[3];
  float* out = (float*)d_out;
  float* tab = (float*)d_ws;          // 133 floats
  int T = in_sizes[1];

  hipLaunchKernelGGL(setup_kernel, dim3(1), dim3(64), 0, stream, tab);
  int ntt = (T + GT - 1) / GT;
  int nb  = (ntt + TPB - 1) / TPB;
  hipLaunchKernelGGL(torsion_kernel, dim3(nb), dim3(BT), 0, stream,
                     dist, angle, phi, idx, tab, out, T);
}

// Round 10
// 126.952 us; speedup vs baseline: 1.2268x; 1.2268x over previous
//
#include <hip/hip_runtime.h>
#include <math.h>

#ifndef M_PI
#define M_PI 3.14159265358979323846
#endif

#define NS 7      // NUM_SPHERICAL
#define NK 6      // NUM_RADIAL
#define GT 64     // triplets per block
#define BT 256    // threads per block
#define NC (NS*NS)   // 49
#define NR (NS*NK)   // 42
#define NF2 147      // float2 per triplet row (294/2)

typedef float f32x2 __attribute__((ext_vector_type(2)));
typedef float f32x4 __attribute__((ext_vector_type(4)));

// tab layout (floats): [0..41] zeros (l*6+j), [42..83] norm, [84..132] coef(49)

// ---------------- setup (f32 hardware trig, ~1us) ---------------------------
__device__ void jl_pair_f(float x, int l, float& jl, float& jm1) {
  float s, c;
  __sincosf(x, &s, &c);
  float invx = 1.0f / x;
  float j0 = s * invx, jm = c * invx;
  if (l == 0) { jl = j0; jm1 = jm; return; }
  float j1 = (s * invx - c) * invx;
  for (int ll = 2; ll <= l; ++ll) {
    float t = (2.0f * ll - 1.0f) * invx * j1 - j0;
    j0 = j1; j1 = t;
  }
  jl = j1; jm1 = j0;
}

__global__ void setup_kernel(float* tab) {
  int id = threadIdx.x;
  if (id < NS * NK) {
    int l = id / NK, j = id % NK;
    float nu = l + 0.5f, mu = 4.0f * nu * nu;
    float b  = ((float)(j + 1) + 0.5f * nu - 0.25f) * (float)M_PI;
    float b8 = 8.0f * b;
    float x = b - (mu - 1.0f) / b8
                - 4.0f * (mu - 1.0f) * (7.0f * mu - 31.0f) / (3.0f * b8 * b8 * b8)
                - 32.0f * (mu - 1.0f) * (83.0f * mu * mu - 982.0f * mu + 3779.0f) /
                  (15.0f * b8 * b8 * b8 * b8 * b8);
    float jl, jm1;
    for (int it = 0; it < 5; ++it) {
      jl_pair_f(x, l, jl, jm1);
      float dj = jm1 - (l + 1.0f) / x * jl;   // j_l'(x)
      x -= jl / dj;
    }
    tab[id] = x;
    jl_pair_f(x, l, jl, jm1);
    float jp1 = (2.0f * l + 1.0f) / x * jl - jm1;   // j_{l+1}(x)
    tab[NS * NK + id] = sqrtf(2.0f) / fabsf(jp1);
  }
  if (id < NC) {
    double v;
    if (id == 0) {
      v = 0.5 / sqrt(M_PI);
    } else {
      int l = 1;
      while ((l + 1) * (l + 1) <= id) ++l;
      int m  = id - l * l - l;
      int am = m < 0 ? -m : m;
      double fr = 1.0;
      for (int i2 = l - am + 1; i2 <= l + am; ++i2) fr *= (double)i2;
      double pref = sqrt((2.0 * l + 1.0) / (4.0 * M_PI * fr));
      v = (m != 0) ? sqrt(2.0) * pref : pref;
    }
    tab[2 * NS * NK + id] = (float)v;
  }
}

// ---------------- main kernel (round-6 skeleton) ----------------------------
__global__ __launch_bounds__(BT, 4) void torsion_kernel(
    const float* __restrict__ dist, const float* __restrict__ angle,
    const float* __restrict__ phi, const int* __restrict__ idx_kj,
    const float* __restrict__ tab, float* __restrict__ out, int T) {
  __shared__ float s_cbf[GT][NC];                       // 64 x 49
  __shared__ __align__(8) float s_rbf[GT][NR];          // 64 x 42
  __shared__ float s_d[GT];
  __shared__ float s_tab[133];
  __shared__ unsigned s_map2[NF2];   // packed: map(cc) | map((cc+1)%147)<<16

  const int tid = threadIdx.x;
  const int t0  = blockIdx.x * GT;
  const int nt  = min(GT, T - t0);

  // ---- phase 0: input loads + LDS tables ----
  float a = 0.0f, ph = 0.0f;
  if (tid < GT) {
    int t = t0 + tid;
    float dd = 1.0f;
    if (t < T) {
      dd = dist[idx_kj[t]] * 0.2f;   // /CUTOFF
      a  = angle[t];
      ph = phi[t];
    }
    s_d[tid] = dd;
  }
  if (tid < 133) s_tab[tid] = tab[tid];
  if (tid < NF2) {
    // map(cc): ii=cc/21, rem2=cc-21*ii, jj=rem2/3 -> (ii*7+jj) | rem2<<8
    auto mk = [](int cc) {
      int ii = (cc * 3121) >> 16;        // cc/21, cc<147
      int rem2 = cc - 21 * ii;
      int jj = (rem2 * 86) >> 8;         // rem2/3, rem2<21
      return (unsigned)((ii * NS + jj) | (rem2 << 8));
    };
    int cc1 = tid + 1; if (cc1 == NF2) cc1 = 0;
    s_map2[tid] = mk(tid) | (mk(cc1) << 16);
  }
  __syncthreads();

  if (tid < GT) {
    // ---- cbf: lanes 0..63, per-m streaming Legendre ----
    if (t0 + tid < T) {
      float z = cosf(a), s = sinf(a);
      float sp, cp;
      sincosf(ph, &sp, &cp);
      float cmv[NS], smv[NS];
      cmv[0] = 1.0f; smv[0] = 0.0f;
      cmv[1] = cp;   smv[1] = sp;
#pragma unroll
      for (int m = 2; m < NS; ++m) {
        cmv[m] = 2.0f * cp * cmv[m - 1] - cmv[m - 2];
        smv[m] = 2.0f * cp * smv[m - 1] - smv[m - 2];
      }
      const float* coef = s_tab + 2 * NR;
      float* crow = s_cbf[tid];
      float pmm = 1.0f;
#pragma unroll
      for (int m = 0; m < NS; ++m) {
        float pl1 = pmm, pl2 = 0.0f;
#pragma unroll
        for (int l = m; l < NS; ++l) {
          float plm;
          if (l == m)          plm = pmm;
          else if (l == m + 1) plm = (float)(2 * m + 1) * z * pmm;
          else                 plm = ((float)(2 * l - 1) * z * pl1 -
                                      (float)(l + m - 1) * pl2) *
                                     (float)(1.0 / (double)(l - m));
          int cpn = l * l + l + m;
          if (m == 0) {
            crow[cpn] = coef[cpn] * plm;
          } else {
            crow[cpn] = coef[cpn] * cmv[m] * plm;
            crow[l * l + l - m] = coef[l * l + l - m] * smv[m] * plm;
          }
          pl2 = pl1; pl1 = plm;
        }
        pmm = (float)(-1 - 2 * m) * s * pmm;   // P[m+1][m+1]
      }
    }
  } else {
    // ---- rbf: threads 64..255 cover 64*42 = 2688 = 14*192 items ----
    int j  = tid - 64;
    int t  = j / NR;
    int cc = j - NR * t;
    int i2 = j;
    float* rlin = &s_rbf[0][0];
#pragma unroll 2
    for (int it = 0; it < 14; ++it) {
      int l = (cc * 43) >> 8;      // cc/6 for cc<42
      float x = s_d[t] * s_tab[cc];
      float sx, cx;
      sincosf(x, &sx, &cx);
      float invx = 1.0f / x;
      float jm = sx * invx;
      float jc;
      if (l == 0) jc = jm;
      else {
        jc = (sx * invx - cx) * invx;
#pragma unroll
        for (int ll = 2; ll <= 6; ++ll) {
          if (ll <= l) {
            float tt = (float)(2 * ll - 1) * invx * jc - jm;
            jm = jc; jc = tt;
          }
        }
      }
      rlin[i2] = s_tab[NR + cc] * jc;
      i2 += 192;
      cc += 24; t += 4;            // 192 = 4*42 + 24
      if (cc >= NR) { cc -= NR; ++t; }
    }
  }
  __syncthreads();

  // ---- store: wave-contiguous monotonic streams, 6-deep register bursts ----
  // wave w stores f32x4 indices [w*1176, (w+1)*1176) of the block's 4704.
  // n = w*1176 + it*64 + lane, it = 0..18 (it==18: lanes 0..23 only).
  const f32x2* r2 = (const f32x2*)&s_rbf[0][0];   // row stride 21 f32x2

  if (nt == GT) {
    const int w    = tid >> 6;
    const int lane = tid & 63;
    const int n0   = w * 1176 + lane;
    int p = n0 / 147;                 // triplet-pair index (0..31)
    int k = n0 - 147 * p;             // f32x4 index within the 588-float pair
    int cc = k << 1; if (cc >= NF2) cc -= NF2;   // (2k) mod 147

    f32x4* o4 = (f32x4*)out + (size_t)blockIdx.x * 4704 + n0;

    auto GATHER = [&]() -> f32x4 {
      int t2 = p << 1;
      int ta = t2 + (k >= 74 ? 1 : 0);    // row of first f32x2 (c2=2k)
      int tb = t2 + (k >= 73 ? 1 : 0);    // row of second f32x2 (c2=2k+1)
      unsigned mp = s_map2[cc];
      unsigned i0 = mp & 0xffu,          r0 = (mp >> 8) & 0xffu;
      unsigned i1 = (mp >> 16) & 0xffu,  r1 = mp >> 24;
      float cv0 = s_cbf[ta][i0];
      f32x2 rv0 = r2[ta * 21 + r0];
      float cv1 = s_cbf[tb][i1];
      f32x2 rv1 = r2[tb * 21 + r1];
      f32x4 ov = {cv0 * rv0.x, cv0 * rv0.y, cv1 * rv1.x, cv1 * rv1.y};
      // advance walk: n += 64
      k += 64;  if (k >= 147) { k -= 147; ++p; }
      cc += 128; if (cc >= NF2) cc -= NF2;
      return ov;
    };

    f32x4 ov[6];
#pragma unroll
    for (int g = 0; g < 3; ++g) {
#pragma unroll
      for (int j = 0; j < 6; ++j) ov[j] = GATHER();
#pragma unroll
      for (int j = 0; j < 6; ++j)
        __builtin_nontemporal_store(ov[j], o4 + (g * 6 + j) * 64);
    }
    if (lane < 24) {                   // it = 18: last 24 f32x4 of the wave
      f32x4 last = GATHER();
      __builtin_nontemporal_store(last, o4 + 18 * 64);
    }
  } else {
    // tail block: float2 path, any nt
    f32x2* o2 = (f32x2*)out + (size_t)t0 * NF2;
    int tot = nt * NF2;
    for (int i = tid; i < tot; i += BT) {
      int t  = i / NF2;
      int c2 = i - NF2 * t;
      unsigned mp = s_map2[c2] & 0xffffu;
      float cv = s_cbf[t][mp & 0xffu];
      f32x2 rv = r2[t * 21 + (mp >> 8)];
      f32x2 ov = cv * rv;
      __builtin_nontemporal_store(ov, o2 + i);
    }
  }
}

// ---------------- launch ----------------------------------------------------
extern "C" void kernel_launch(void* const* d_in, const int* in_sizes, int n_in,
                              void* d_out, int out_size, void* d_ws, size_t ws_size,
                              hipStream_t stream) {
  const float* dist  = (const float*)d_in[0];
  const float* angle = (const float*)d_in[1];
  const float* phi   = (const float*)d_in[2];
  const int*   idx   = (const int*)d_in[3];
  float* out = (float*)d_out;
  float* tab = (float*)d_ws;          // 133 floats
  int T = in_sizes[1];

  hipLaunchKernelGGL(setup_kernel, dim3(1), dim3(64), 0, stream, tab);
  int nb = (T + GT - 1) / GT;
  hipLaunchKernelGGL(torsion_kernel, dim3(nb), dim3(BT), 0, stream,
                     dist, angle, phi, idx, tab, out, T);
}

// Round 11
// 122.786 us; speedup vs baseline: 1.2685x; 1.0339x over previous
//
#include <hip/hip_runtime.h>
#include <math.h>

#ifndef M_PI
#define M_PI 3.14159265358979323846
#endif

#define NS 7      // NUM_SPHERICAL
#define NK 6      // NUM_RADIAL
#define GT 64     // triplets per block
#define BT 256    // threads per block
#define NC (NS*NS)   // 49
#define NR (NS*NK)   // 42
#define NF2 147      // float2 per triplet row (294/2)

typedef float f32x2 __attribute__((ext_vector_type(2)));
typedef float f32x4 __attribute__((ext_vector_type(4)));

// tab layout (floats): [0..41] zeros (l*6+j), [42..83] norm, [84..132] coef(49)

// ---------------- setup (f32 hardware trig, ~1us) ---------------------------
__device__ void jl_pair_f(float x, int l, float& jl, float& jm1) {
  float s, c;
  __sincosf(x, &s, &c);
  float invx = 1.0f / x;
  float j0 = s * invx, jm = c * invx;
  if (l == 0) { jl = j0; jm1 = jm; return; }
  float j1 = (s * invx - c) * invx;
  for (int ll = 2; ll <= l; ++ll) {
    float t = (2.0f * ll - 1.0f) * invx * j1 - j0;
    j0 = j1; j1 = t;
  }
  jl = j1; jm1 = j0;
}

__global__ void setup_kernel(float* tab) {
  int id = threadIdx.x;
  if (id < NS * NK) {
    int l = id / NK, j = id % NK;
    float nu = l + 0.5f, mu = 4.0f * nu * nu;
    float b  = ((float)(j + 1) + 0.5f * nu - 0.25f) * (float)M_PI;
    float b8 = 8.0f * b;
    float x = b - (mu - 1.0f) / b8
                - 4.0f * (mu - 1.0f) * (7.0f * mu - 31.0f) / (3.0f * b8 * b8 * b8)
                - 32.0f * (mu - 1.0f) * (83.0f * mu * mu - 982.0f * mu + 3779.0f) /
                  (15.0f * b8 * b8 * b8 * b8 * b8);
    float jl, jm1;
    for (int it = 0; it < 5; ++it) {
      jl_pair_f(x, l, jl, jm1);
      float dj = jm1 - (l + 1.0f) / x * jl;   // j_l'(x)
      x -= jl / dj;
    }
    tab[id] = x;
    jl_pair_f(x, l, jl, jm1);
    float jp1 = (2.0f * l + 1.0f) / x * jl - jm1;   // j_{l+1}(x)
    tab[NS * NK + id] = sqrtf(2.0f) / fabsf(jp1);
  }
  if (id < NC) {
    double v;
    if (id == 0) {
      v = 0.5 / sqrt(M_PI);
    } else {
      int l = 1;
      while ((l + 1) * (l + 1) <= id) ++l;
      int m  = id - l * l - l;
      int am = m < 0 ? -m : m;
      double fr = 1.0;
      for (int i2 = l - am + 1; i2 <= l + am; ++i2) fr *= (double)i2;
      double pref = sqrt((2.0 * l + 1.0) / (4.0 * M_PI * fr));
      v = (m != 0) ? sqrt(2.0) * pref : pref;
    }
    tab[2 * NS * NK + id] = (float)v;
  }
}

// ---------------- main kernel (round-10 skeleton, 6 blocks/CU) --------------
__global__ __launch_bounds__(BT, 6) void torsion_kernel(
    const float* __restrict__ dist, const float* __restrict__ angle,
    const float* __restrict__ phi, const int* __restrict__ idx_kj,
    const float* __restrict__ tab, float* __restrict__ out, int T) {
  __shared__ float s_cbf[GT][NC];                       // 64 x 49
  __shared__ __align__(8) float s_rbf[GT][NR];          // 64 x 42
  __shared__ float s_d[GT];
  __shared__ float s_tab[133];
  __shared__ unsigned s_map2[NF2];   // packed: map(cc) | map((cc+1)%147)<<16

  const int tid = threadIdx.x;
  const int t0  = blockIdx.x * GT;
  const int nt  = min(GT, T - t0);

  // ---- phase 0: input loads + LDS tables ----
  float a = 0.0f, ph = 0.0f;
  if (tid < GT) {
    int t = t0 + tid;
    float dd = 1.0f;
    if (t < T) {
      dd = dist[idx_kj[t]] * 0.2f;   // /CUTOFF
      a  = angle[t];
      ph = phi[t];
    }
    s_d[tid] = dd;
  }
  if (tid < 133) s_tab[tid] = tab[tid];
  if (tid < NF2) {
    // map(cc): ii=cc/21, rem2=cc-21*ii, jj=rem2/3 -> (ii*7+jj) | rem2<<8
    auto mk = [](int cc) {
      int ii = (cc * 3121) >> 16;        // cc/21, cc<147
      int rem2 = cc - 21 * ii;
      int jj = (rem2 * 86) >> 8;         // rem2/3, rem2<21
      return (unsigned)((ii * NS + jj) | (rem2 << 8));
    };
    int cc1 = tid + 1; if (cc1 == NF2) cc1 = 0;
    s_map2[tid] = mk(tid) | (mk(cc1) << 16);
  }
  __syncthreads();

  if (tid < GT) {
    // ---- cbf: lanes 0..63, per-m streaming Legendre ----
    if (t0 + tid < T) {
      float z, s;
      __sincosf(a, &s, &z);              // s=sin, z=cos
      float sp, cp;
      __sincosf(ph, &sp, &cp);
      float cmv[NS], smv[NS];
      cmv[0] = 1.0f; smv[0] = 0.0f;
      cmv[1] = cp;   smv[1] = sp;
#pragma unroll
      for (int m = 2; m < NS; ++m) {
        cmv[m] = 2.0f * cp * cmv[m - 1] - cmv[m - 2];
        smv[m] = 2.0f * cp * smv[m - 1] - smv[m - 2];
      }
      const float* coef = s_tab + 2 * NR;
      float* crow = s_cbf[tid];
      float pmm = 1.0f;
#pragma unroll
      for (int m = 0; m < NS; ++m) {
        float pl1 = pmm, pl2 = 0.0f;
#pragma unroll
        for (int l = m; l < NS; ++l) {
          float plm;
          if (l == m)          plm = pmm;
          else if (l == m + 1) plm = (float)(2 * m + 1) * z * pmm;
          else                 plm = ((float)(2 * l - 1) * z * pl1 -
                                      (float)(l + m - 1) * pl2) *
                                     (float)(1.0 / (double)(l - m));
          int cpn = l * l + l + m;
          if (m == 0) {
            crow[cpn] = coef[cpn] * plm;
          } else {
            crow[cpn] = coef[cpn] * cmv[m] * plm;
            crow[l * l + l - m] = coef[l * l + l - m] * smv[m] * plm;
          }
          pl2 = pl1; pl1 = plm;
        }
        pmm = (float)(-1 - 2 * m) * s * pmm;   // P[m+1][m+1]
      }
    }
  } else {
    // ---- rbf: threads 64..255 cover 64*42 = 2688 = 14*192 items ----
    int j  = tid - 64;
    int t  = j / NR;
    int cc = j - NR * t;
    int i2 = j;
    float* rlin = &s_rbf[0][0];
#pragma unroll 2
    for (int it = 0; it < 14; ++it) {
      int l = (cc * 43) >> 8;      // cc/6 for cc<42
      float x = s_d[t] * s_tab[cc];
      float sx, cx;
      __sincosf(x, &sx, &cx);
      float invx = 1.0f / x;
      float jm = sx * invx;
      float jc;
      if (l == 0) jc = jm;
      else {
        jc = (sx * invx - cx) * invx;
#pragma unroll
        for (int ll = 2; ll <= 6; ++ll) {
          if (ll <= l) {
            float tt = (float)(2 * ll - 1) * invx * jc - jm;
            jm = jc; jc = tt;
          }
        }
      }
      rlin[i2] = s_tab[NR + cc] * jc;
      i2 += 192;
      cc += 24; t += 4;            // 192 = 4*42 + 24
      if (cc >= NR) { cc -= NR; ++t; }
    }
  }
  __syncthreads();

  // ---- store: wave-contiguous monotonic streams, 6-deep register bursts ----
  const f32x2* r2 = (const f32x2*)&s_rbf[0][0];   // row stride 21 f32x2

  if (nt == GT) {
    const int w    = tid >> 6;
    const int lane = tid & 63;
    const int n0   = w * 1176 + lane;
    int p = n0 / 147;                 // triplet-pair index (0..31)
    int k = n0 - 147 * p;             // f32x4 index within the 588-float pair
    int cc = k << 1; if (cc >= NF2) cc -= NF2;   // (2k) mod 147

    f32x4* o4 = (f32x4*)out + (size_t)blockIdx.x * 4704 + n0;

    auto GATHER = [&]() -> f32x4 {
      int t2 = p << 1;
      int ta = t2 + (k >= 74 ? 1 : 0);    // row of first f32x2 (c2=2k)
      int tb = t2 + (k >= 73 ? 1 : 0);    // row of second f32x2 (c2=2k+1)
      unsigned mp = s_map2[cc];
      unsigned i0 = mp & 0xffu,          r0 = (mp >> 8) & 0xffu;
      unsigned i1 = (mp >> 16) & 0xffu,  r1 = mp >> 24;
      float cv0 = s_cbf[ta][i0];
      f32x2 rv0 = r2[ta * 21 + r0];
      float cv1 = s_cbf[tb][i1];
      f32x2 rv1 = r2[tb * 21 + r1];
      f32x4 ov = {cv0 * rv0.x, cv0 * rv0.y, cv1 * rv1.x, cv1 * rv1.y};
      // advance walk: n += 64
      k += 64;  if (k >= 147) { k -= 147; ++p; }
      cc += 128; if (cc >= NF2) cc -= NF2;
      return ov;
    };

    f32x4 ov[6];
#pragma unroll
    for (int g = 0; g < 3; ++g) {
#pragma unroll
      for (int j = 0; j < 6; ++j) ov[j] = GATHER();
#pragma unroll
      for (int j = 0; j < 6; ++j)
        __builtin_nontemporal_store(ov[j], o4 + (g * 6 + j) * 64);
    }
    if (lane < 24) {                   // it = 18: last 24 f32x4 of the wave
      f32x4 last = GATHER();
      __builtin_nontemporal_store(last, o4 + 18 * 64);
    }
  } else {
    // tail block: float2 path, any nt
    f32x2* o2 = (f32x2*)out + (size_t)t0 * NF2;
    int tot = nt * NF2;
    for (int i = tid; i < tot; i += BT) {
      int t  = i / NF2;
      int c2 = i - NF2 * t;
      unsigned mp = s_map2[c2] & 0xffffu;
      float cv = s_cbf[t][mp & 0xffu];
      f32x2 rv = r2[t * 21 + (mp >> 8)];
      f32x2 ov = cv * rv;
      __builtin_nontemporal_store(ov, o2 + i);
    }
  }
}

// ---------------- launch ----------------------------------------------------
extern "C" void kernel_launch(void* const* d_in, const int* in_sizes, int n_in,
                              void* d_out, int out_size, void* d_ws, size_t ws_size,
                              hipStream_t stream) {
  const float* dist  = (const float*)d_in[0];
  const float* angle = (const float*)d_in[1];
  const float* phi   = (const float*)d_in[2];
  const int*   idx   = (const int*)d_in[3];
  float* out = (float*)d_out;
  float* tab = (float*)d_ws;          // 133 floats
  int T = in_sizes[1];

  hipLaunchKernelGGL(setup_kernel, dim3(1), dim3(64), 0, stream, tab);
  int nb = (T + GT - 1) / GT;
  hipLaunchKernelGGL(torsion_kernel, dim3(nb), dim3(BT), 0, stream,
                     dist, angle, phi, idx, tab, out, T);
}